// Round 2
// baseline (136.618 us; speedup 1.0000x reference)
//
#include <hip/hip_runtime.h>
#include <hip/hip_bf16.h>

// MoE top-1: N=8192 tokens, D=256, H=64, E=32, fp32.
// Baseline: one block (256 thr) per token, fully fused router+argmax+FFN.

constexpr int D = 256;
constexpr int H = 64;
constexpr int E = 32;

__global__ __launch_bounds__(256) void moe_top1_kernel(
    const float* __restrict__ x,    // [N, D]
    const float* __restrict__ rw,   // [E, D]
    const float* __restrict__ rb,   // [E]
    const float* __restrict__ W1,   // [E, D, H]
    const float* __restrict__ b1,   // [E, H]
    const float* __restrict__ W2,   // [E, H, D]
    const float* __restrict__ b2,   // [E, D]
    float* __restrict__ out)        // [N, D]
{
    __shared__ float xs[D];          // token row
    __shared__ float red[8 * E];     // router partials [part][e]
    __shared__ float logits[E];
    __shared__ float hred[4][H];     // FFN1 partials [part][h]
    __shared__ float hs[H];          // hidden (post-relu)

    const int n = blockIdx.x;
    const int t = threadIdx.x;

    // stage x row (coalesced, 1 float/thread)
    xs[t] = x[n * D + t];
    __syncthreads();

    // ---- router: logits[e] = dot(x, rw[e]) + rb[e] ----
    // 8 parts x 32 experts: e = t&31, part = t>>5, each sums 32 d's.
    {
        const int e = t & 31, part = t >> 5;
        const float* w  = rw + e * D + part * 32;
        const float* xp = xs + part * 32;
        float s = 0.f;
#pragma unroll
        for (int k = 0; k < 32; ++k) s += xp[k] * w[k];
        red[part * E + e] = s;
    }
    __syncthreads();
    if (t < E) {
        float s = rb[t];
#pragma unroll
        for (int p = 0; p < 8; ++p) s += red[p * E + t];
        logits[t] = s;
    }
    __syncthreads();

    // ---- argmax (replicated in every thread; identical LDS inputs) ----
    // strict '>' keeps first occurrence, matching jnp.argmax tie-break.
    int eidx;
    {
        float best = logits[0];
        int bi = 0;
#pragma unroll
        for (int i = 1; i < E; ++i) {
            float v = logits[i];
            if (v > best) { best = v; bi = i; }
        }
        eidx = bi;
    }

    // ---- FFN1: h[j] = relu(sum_d x[d] * W1[e][d][j] + b1[e][j]) ----
    // 4 waves x 64-d chunks; lane j = output h index (coalesced W1 reads).
    {
        const int j = t & 63, p4 = t >> 6;
        const float* w  = W1 + (size_t)eidx * (D * H) + p4 * 64 * H + j;
        const float* xp = xs + p4 * 64;
        float s = 0.f;
#pragma unroll
        for (int k = 0; k < 64; ++k) s += xp[k] * w[k * H];
        hred[p4][j] = s;
    }
    __syncthreads();
    if (t < H) {
        float s = b1[eidx * H + t];
#pragma unroll
        for (int p = 0; p < 4; ++p) s += hred[p][t];
        hs[t] = fmaxf(s, 0.f);
    }
    __syncthreads();

    // ---- FFN2: out[i] = relu(sum_h hs[h] * W2[e][h][i] + b2[e][i]) ----
    // thread t = output column i; W2 reads coalesced, hs broadcast.
    {
        const float* w = W2 + (size_t)eidx * (H * D) + t;
        float s = b2[eidx * D + t];
#pragma unroll
        for (int k = 0; k < H; ++k) s += hs[k] * w[k * D];
        out[n * D + t] = fmaxf(s, 0.f);
    }
}

extern "C" void kernel_launch(void* const* d_in, const int* in_sizes, int n_in,
                              void* d_out, int out_size, void* d_ws, size_t ws_size,
                              hipStream_t stream) {
    const float* x  = (const float*)d_in[0];
    const float* rw = (const float*)d_in[1];
    const float* rb = (const float*)d_in[2];
    const float* W1 = (const float*)d_in[3];
    const float* b1 = (const float*)d_in[4];
    const float* W2 = (const float*)d_in[5];
    const float* b2 = (const float*)d_in[6];
    float* out = (float*)d_out;

    const int N = in_sizes[0] / D;   // 8192 tokens

    moe_top1_kernel<<<N, 256, 0, stream>>>(x, rw, rb, W1, b1, W2, b2, out);
}